// Round 1
// baseline (1808.223 us; speedup 1.0000x reference)
//
#include <hip/hip_runtime.h>
#include <cstdint>
#include <cstddef>

// ===========================================================================
// ActionDecoder on MI355X — round 13: TAG-IN-DATA sync (flagless, ack-free).
// r12 chain per step serialized 3 agent-scope (IC) round trips:
//   h-store ack (vmcnt0 drain at release barrier) -> flag store+visibility ->
//   poll detect -> separate A-load.
// r13: each h col-pair is published as ONE 8-byte relaxed agent-scope atomic
// {f16x2 value | u32 step-tag}. 8B aligned atomic stores are single-copy
// atomic, so tag==t+1 guarantees the f16x2 beside it is step-t data.
//   - poll IS the A-load: re-issue 8x global_load_dwordx4 sc1 until all 16
//     embedded tags == t+1 (exact match; 0xAA poison / stale tags never
//     collide: tags are 1..513).
//   - producer publish is fire-and-forget: NO vmcnt ack, NO flag, NO release
//     barrier. One barrier/step remains (split-K LDS reduce).
//   - Spart double-buffered by t&1 (80KB LDS) to close the write(t+1) vs
//     read(t) race the removed barrier used to prevent. hbuf 2-deep recycle
//     stays safe: h_{t+2} store is behind barrier(t+1) which is behind all
//     waves' tagged reads of h_t (distance-2 through the per-step barrier).
// Rest identical to r7/r12: 64 WGs (BG=wg>>4, CG=wg&15), wave wv owns
// K-chunk [128wv,128wv+128), B-frags in 128 VGPRs, split-K partials in LDS
// pitch 20, gates on (batch-loc, 2 adjacent cols) threads, P-row prefetch in
// the poll shadow.
// ===========================================================================

typedef _Float16     f16x8 __attribute__((ext_vector_type(8)));
typedef _Float16     f16x2 __attribute__((ext_vector_type(2)));
typedef float        f32x4 __attribute__((ext_vector_type(4)));
typedef float        f32x2 __attribute__((ext_vector_type(2)));
typedef unsigned int u32x4 __attribute__((ext_vector_type(4)));

#define TPB 256
#define NWG 64

// ---- ws layout (bytes) ----
#define WS_GX0   0          // 64*2048 f32   = 524288
#define WS_P     524288     // 512*2048 f32  = 4194304
#define WS_HN    4718592    // 64*512 f32    = 131072
#define WS_HBUF  4849664    // 2*64*256 u64  = 262144  (tagged h col-pairs)

__device__ __forceinline__ float sigm_(float x) { return 1.f / (1.f + __expf(-x)); }
__device__ __forceinline__ float tanh_(float x) {
    const float e = __expf(-2.f * fabsf(x));
    return copysignf((1.f - e) / (1.f + e), x);
}

// ---------------------------------------------------------------------------
// Generic f32 tiled GEMM: C[M,N] = A[M,K] @ B[N,K]^T (+bias1+bias2 on z==0).
// ---------------------------------------------------------------------------
__global__ void gemm_nt_bias(const float* __restrict__ A, int lda,
                             const float* __restrict__ B, int ldb,
                             float* __restrict__ C, int ldc, int K,
                             const float* __restrict__ bias1,
                             const float* __restrict__ bias2)
{
    __shared__ float As[32 * 68];
    __shared__ float Bs[32 * 68];
    const int tid = threadIdx.x;
    const int m0 = blockIdx.y * 64, n0 = blockIdx.x * 64;
    const int kchunk = K / gridDim.z;
    const int kbeg = blockIdx.z * kchunk, kend = kbeg + kchunk;
    const int tr = tid >> 4, tc = tid & 15;
    float acc[4][4] = {};

    for (int k0 = kbeg; k0 < kend; k0 += 32) {
        __syncthreads();
        #pragma unroll
        for (int idx = tid; idx < 2048; idx += TPB) {
            const int r = idx >> 5, kk = idx & 31;
            As[kk * 68 + r] = A[(size_t)(m0 + r) * lda + k0 + kk];
            Bs[kk * 68 + r] = B[(size_t)(n0 + r) * ldb + k0 + kk];
        }
        __syncthreads();
        #pragma unroll
        for (int kk = 0; kk < 32; ++kk) {
            const f32x4 a = *(const f32x4*)&As[kk * 68 + tr * 4];
            const f32x4 b = *(const f32x4*)&Bs[kk * 68 + tc * 4];
            #pragma unroll
            for (int i = 0; i < 4; ++i)
                #pragma unroll
                for (int j = 0; j < 4; ++j)
                    acc[i][j] = fmaf(a[i], b[j], acc[i][j]);
        }
    }

    const bool split = (gridDim.z > 1);
    #pragma unroll
    for (int i = 0; i < 4; ++i) {
        const int m = m0 + tr * 4 + i;
        #pragma unroll
        for (int j = 0; j < 4; ++j) {
            const int n = n0 + tc * 4 + j;
            float v = acc[i][j];
            if (blockIdx.z == 0) {
                if (bias1) v += bias1[n];
                if (bias2) v += bias2[n];
            }
            if (split) atomicAdd(&C[(size_t)m * ldc + n], v);
            else       C[(size_t)m * ldc + n] = v;
        }
    }
}

// ---------------------------------------------------------------------------
// LSTM recurrence. 64 WGs x 256 threads. 2-D partition, split-K per wave.
// hbuf: [2][64 batches][256 col-pairs] of u64 = {f16x2 h | u32 tag}.
//   tag convention: h_t carries tag t+1 (h_0 init -> tag 1).
// ---------------------------------------------------------------------------
__global__ void __launch_bounds__(TPB, 1)
lstm_seq(const float* __restrict__ Whh,   // [2048,512] f32
         const float* __restrict__ GX0,   // [64,2048] f32 (ws)
         const float* __restrict__ P,     // [512,2048] f32 (ws)
         const int*   __restrict__ x2,    // [64,512]
         const int*   __restrict__ lens,  // [64]
         unsigned long long* hbuf,        // [2][64*256] tagged pairs (ws)
         float*       __restrict__ hn)    // [64,512] f32 (ws)
{
    // Spart[buf][wv][rowloc(128)][batch(16)+pad4] f32 — DOUBLE buffered
    __shared__ float Spart[2 * 4 * 128 * 20];   // 81920 B

    const int tid = threadIdx.x, wg = blockIdx.x;
    const int lane = tid & 63, wv = tid >> 6;
    const int BG = wg >> 4;               // batch group 0..3
    const int CG = wg & 15;               // col group 0..15
    const int m16 = lane & 15, q = lane >> 4;

    // ---- gate-thread geometry: thread -> (batch-loc, 2 adjacent cols) ----
    const int bl  = tid >> 4;             // 0..15 batch-local
    const int cq  = (tid & 15) * 2;       // 0,2,..,30 col-local
    const int b   = BG * 16 + bl;
    const int col = CG * 32 + cq;
    const int cp  = CG * 16 + (tid & 15); // col-pair index 0..255
    const int last = lens[b] - 1;
    const int* toks = x2 + b * 512;

    // ---- time-invariant gate inputs from GX0 (hoisted) ----
    f32x2 gxv[4];
    {
        const float* gx = GX0 + (size_t)b * 2048 + col;
        #pragma unroll
        for (int g = 0; g < 4; ++g) gxv[g] = *(const f32x2*)(gx + g * 512);
    }

    // ---- publish h_0 = 0 with tag 1 (fire-and-forget, pollers wait) ----
    __hip_atomic_store(hbuf + (size_t)b * 256 + cp,
                       (unsigned long long)1u << 32,
                       __ATOMIC_RELAXED, __HIP_MEMORY_SCOPE_AGENT);

    // ---- B fragments: wave wv's 8 n-tiles x 4 K-frags (128 VGPRs) ----
    f16x8 bfr[8][4];
    #pragma unroll
    for (int n = 0; n < 8; ++n) {
        const int rr = n * 16 + m16;
        const int gr = (rr >> 5) * 512 + CG * 32 + (rr & 31);
        const float* wrow = Whh + (size_t)gr * 512 + wv * 128 + q * 8;
        #pragma unroll
        for (int ks = 0; ks < 4; ++ks) {
            const f32x4 w0 = *(const f32x4*)(wrow + ks * 32);
            const f32x4 w1 = *(const f32x4*)(wrow + ks * 32 + 4);
            f16x8 bv;
            #pragma unroll
            for (int e = 0; e < 4; ++e) {
                bv[e]     = (_Float16)w0[e];
                bv[4 + e] = (_Float16)w1[e];
            }
            bfr[n][ks] = bv;
        }
    }

    // ---- consumer A base: unit index (8B units) for my K-chunk ----
    const unsigned long long* abase =
        hbuf + (size_t)(BG * 16 + m16) * 256 + wv * 64 + q * 4;

    // ---- P-row pipeline: ppv = row for step t; refilled post-publish ----
    int tok1;
    f32x2 ppv[4];
    {
        const int tok0 = toks[0];
        const float* pp = P + (size_t)tok0 * 2048 + col;
        #pragma unroll
        for (int g = 0; g < 4; ++g) ppv[g] = *(const f32x2*)(pp + g * 512);
        tok1 = toks[1];
    }

    float c0 = 0.f, c1 = 0.f;

    for (int t = 0; t < 512; ++t) {
        const unsigned int tgt = (unsigned int)(t + 1);
        const unsigned long long* hs = abase + (size_t)(t & 1) * 16384;

        // ---- poll == A-load: 8 x dwordx4 sc1 (tagged pairs); retry until
        //      all 16 embedded tags == tgt. vmcnt(0) also drains the P
        //      prefetch issued last step (overlapped, ~free). ----
        u32x4 r0, r1, r2, r3, r4, r5, r6, r7;
        while (true) {
            asm volatile(
                "global_load_dwordx4 %0, %8, off sc1\n\t"
                "global_load_dwordx4 %1, %8, off offset:16 sc1\n\t"
                "global_load_dwordx4 %2, %8, off offset:128 sc1\n\t"
                "global_load_dwordx4 %3, %8, off offset:144 sc1\n\t"
                "global_load_dwordx4 %4, %8, off offset:256 sc1\n\t"
                "global_load_dwordx4 %5, %8, off offset:272 sc1\n\t"
                "global_load_dwordx4 %6, %8, off offset:384 sc1\n\t"
                "global_load_dwordx4 %7, %8, off offset:400 sc1\n\t"
                "s_waitcnt vmcnt(0)"
                : "=&v"(r0), "=&v"(r1), "=&v"(r2), "=&v"(r3),
                  "=&v"(r4), "=&v"(r5), "=&v"(r6), "=&v"(r7)
                : "v"(hs)
                : "memory");
            const unsigned int d =
                (r0[1] ^ tgt) | (r0[3] ^ tgt) | (r1[1] ^ tgt) | (r1[3] ^ tgt) |
                (r2[1] ^ tgt) | (r2[3] ^ tgt) | (r3[1] ^ tgt) | (r3[3] ^ tgt) |
                (r4[1] ^ tgt) | (r4[3] ^ tgt) | (r5[1] ^ tgt) | (r5[3] ^ tgt) |
                (r6[1] ^ tgt) | (r6[3] ^ tgt) | (r7[1] ^ tgt) | (r7[3] ^ tgt);
            if (__all((int)(d == 0u))) break;
        }

        // ---- strip tags -> A fragments (value words are even dwords) ----
        u32x4 fw0 = {r0[0], r0[2], r1[0], r1[2]};
        u32x4 fw1 = {r2[0], r2[2], r3[0], r3[2]};
        u32x4 fw2 = {r4[0], r4[2], r5[0], r5[2]};
        u32x4 fw3 = {r6[0], r6[2], r7[0], r7[2]};
        f16x8 af[4] = {
            __builtin_bit_cast(f16x8, fw0), __builtin_bit_cast(f16x8, fw1),
            __builtin_bit_cast(f16x8, fw2), __builtin_bit_cast(f16x8, fw3)
        };

        // ---- 32 MFMA: 8 n-tiles x 4 K-steps (my K-chunk partial) ----
        f32x4 acc[8] = {};
        #pragma unroll
        for (int ks = 0; ks < 4; ++ks)
            #pragma unroll
            for (int n = 0; n < 8; ++n)
                acc[n] = __builtin_amdgcn_mfma_f32_16x16x32_f16(
                    af[ks], bfr[n][ks], acc[n], 0, 0, 0);

        // ---- write partial S to LDS buf t&1: [wv][n*16+cl][r0..r0+3] ----
        float* sp = Spart + (t & 1) * 10240;
        {
            const int cl = lane & 15, rr = (lane >> 4) * 4;
            #pragma unroll
            for (int n = 0; n < 8; ++n)
                *(f32x4*)&sp[(wv * 128 + n * 16 + cl) * 20 + rr] = acc[n];
        }
        __syncthreads();                  // split-K reduction barrier (only one)

        // ---- gate inputs: sum 4 wave-partials per gate value ----
        f32x2 sv[4];
        #pragma unroll
        for (int g = 0; g < 4; ++g) {
            f32x2 s = {0.f, 0.f};
            #pragma unroll
            for (int w = 0; w < 4; ++w) {
                const int base = (w * 128 + g * 32 + cq) * 20 + bl;
                s[0] += sp[base];
                s[1] += sp[base + 20];
            }
            sv[g] = s;
        }

        // ---- gates (2 adjacent cols of one batch per thread) ----
        float hv[2];
        #pragma unroll
        for (int p = 0; p < 2; ++p) {
            const float iv = sigm_(sv[0][p] + gxv[0][p] + ppv[0][p]);
            const float fv = sigm_(sv[1][p] + gxv[1][p] + ppv[1][p]);
            const float gv = tanh_(sv[2][p] + gxv[2][p] + ppv[2][p]);
            const float ov = sigm_(sv[3][p] + gxv[3][p] + ppv[3][p]);
            float& c = p ? c1 : c0;
            c = fv * c + iv * gv;
            hv[p] = ov * tanh_(c);
        }

        // ---- publish tagged h pair: ONE 8B atomic, fire-and-forget.
        //      No ack, no flag, no release barrier. ----
        f16x2 hh; hh[0] = (_Float16)hv[0]; hh[1] = (_Float16)hv[1];
        const unsigned long long pv =
            ((unsigned long long)(unsigned int)(t + 2) << 32) |
            (unsigned long long)__builtin_bit_cast(unsigned int, hh);
        __hip_atomic_store(hbuf + (size_t)((t + 1) & 1) * 16384
                                + (size_t)b * 256 + cp,
                           pv, __ATOMIC_RELAXED, __HIP_MEMORY_SCOPE_AGENT);

        if (t == last) {
            f32x2 o; o[0] = hv[0]; o[1] = hv[1];
            *(f32x2*)(hn + (size_t)b * 512 + col) = o;
        }

        // ---- NEXT step's P row prefetch: latency parks in the poll window
        //      (its vmcnt drains together with the poll loads). ----
        {
            const float* pn = P + (size_t)tok1 * 2048 + col;
            #pragma unroll
            for (int g = 0; g < 4; ++g)
                ppv[g] = *(const f32x2*)(pn + g * 512);
            tok1 = toks[t < 510 ? t + 2 : 511];
        }
    }
}

// ---------------------------------------------------------------------------
extern "C" void kernel_launch(void* const* d_in, const int* in_sizes, int n_in,
                              void* d_out, int out_size, void* d_ws, size_t ws_size,
                              hipStream_t stream)
{
    const float* x1    = (const float*)d_in[0];   // [64,1024]
    const int*   x2    = (const int*)  d_in[1];   // [64,512]
    const int*   lens  = (const int*)  d_in[2];   // [64]
    const float* emb   = (const float*)d_in[3];   // [512,128]
    const float* W_ih  = (const float*)d_in[4];   // [2048,1152]
    const float* W_hh  = (const float*)d_in[5];   // [2048,512]
    const float* b_ih  = (const float*)d_in[6];   // [2048]
    const float* b_hh  = (const float*)d_in[7];   // [2048]
    const float* W_act = (const float*)d_in[8];   // [512,512]
    const float* b_act = (const float*)d_in[9];   // [512]
    float* out = (float*)d_out;                   // [64,512]

    char* ws = (char*)d_ws;
    float*              GX0  = (float*)(ws + WS_GX0);
    float*              P    = (float*)(ws + WS_P);
    float*              hn   = (float*)(ws + WS_HN);
    unsigned long long* hbuf = (unsigned long long*)(ws + WS_HBUF);

    // zero k-split accumulators (ws/out poisoned 0xAA each call; 0xAAAAAAAA
    // never collides with tags 1..513, so hbuf needs no reset)
    hipMemsetAsync(GX0, 0, 64 * 2048 * sizeof(float), stream);
    hipMemsetAsync(out, 0, 64 * 512 * sizeof(float), stream);

    // GX0 = x1 @ W_ih[:, :1024]^T + b_ih + b_hh    (K=1024, 4-way K-split)
    gemm_nt_bias<<<dim3(32, 1, 4), TPB, 0, stream>>>(
        x1, 1024, W_ih, 1152, GX0, 2048, 1024, b_ih, b_hh);
    // P = emb @ W_ih[:, 1024:]^T                   (K=128)
    gemm_nt_bias<<<dim3(32, 8, 1), TPB, 0, stream>>>(
        emb, 128, W_ih + 1024, 1152, P, 2048, 128, nullptr, nullptr);

    // recurrence: 64 WGs, tag-in-data sync (flagless, ack-free)
    lstm_seq<<<NWG, TPB, 0, stream>>>(W_hh, GX0, P, x2, lens, hbuf, hn);

    // out = hn @ W_act^T + b_act                   (K=512, 4-way K-split)
    gemm_nt_bias<<<dim3(8, 1, 4), TPB, 0, stream>>>(
        hn, 512, W_act, 512, out, 512, 512, b_act, nullptr);
}

// Round 2
// 1708.767 us; speedup vs baseline: 1.0582x; 1.0582x over previous
//
#include <hip/hip_runtime.h>
#include <cstdint>
#include <cstddef>

// ===========================================================================
// ActionDecoder on MI355X — round 14: r12 core (proven 1285us lstm) + two
// independent latency cuts. r13's tag-in-data REVERTED (post-mortem: publish
// store is vmcnt-tracked so its ack stayed on the critical path inside the
// poll's vmcnt(0), and the 8KB/wave spin re-loads congested the fabric:
// FETCH 152->269MB, one 32.8ms collapse).
// r14 changes vs r12:
//  (1) PER-WAVE flags replace {release barrier + WG flag}: each wave does
//      h-store -> s_waitcnt vmcnt(0) (its own stores) -> lane0 flag. No bar2,
//      no WG-straggler wait at release. Consumers poll 16 per-wave flags
//      (4 producer WGs x 4 waves, lane&15 mapping). Safety: bar1 (split-K
//      reduce barrier) still couples the 4 waves each step, so the r12
//      distance-2 hbuf recycle argument holds wave-for-WG; Spart becomes
//      double-buffered (t&1, 80KB LDS) to close the read(t)/write(t+1) race
//      bar2 used to cover.
//  (2) Spart granule rotation kills the 4-way reduce-read bank conflicts
//      (SQ_LDS_BANK_CONFLICT 2.5e7/dispatch): batch-granule position
//      p = (gq + (row>>3)) & 3 on write (b128-preserving) and read makes
//      both sides exactly 2-way (free, m136). Col-pair +20 read never
//      crosses an 8-row rotation boundary (cq even).
// Topology unchanged: 64 WGs, WG w = (BG=w>>4, CG=w&15) owns 16 batches x
// 32 h-cols; wave wv takes K-chunk [128wv,128wv+128), B-frags in 128 VGPRs,
// split-K partials in LDS pitch 20, gates on (batch-loc, 2 adjacent cols)
// threads, P-row prefetch post-release (poll-shadow), relaxed agent-scope
// (sc1, IC-coherent) cross-WG data/flags.
// ===========================================================================

typedef _Float16     f16x8 __attribute__((ext_vector_type(8)));
typedef _Float16     f16x2 __attribute__((ext_vector_type(2)));
typedef float        f32x4 __attribute__((ext_vector_type(4)));
typedef float        f32x2 __attribute__((ext_vector_type(2)));
typedef unsigned int u32x4 __attribute__((ext_vector_type(4)));

#define TPB 256
#define NWG 64

// ---- ws layout (bytes) ----
#define WS_GX0   0          // 64*2048 f32   = 524288
#define WS_P     524288     // 512*2048 f32  = 4194304
#define WS_HN    4718592    // 64*512 f32    = 131072
#define WS_HBUF  4849664    // 2*64*512 f16  = 131072
#define WS_FLAGS 4980736    // 256 wave-slots x 64B = 16384

__device__ __forceinline__ float sigm_(float x) { return 1.f / (1.f + __expf(-x)); }
__device__ __forceinline__ float tanh_(float x) {
    const float e = __expf(-2.f * fabsf(x));
    return copysignf((1.f - e) / (1.f + e), x);
}

// agent-scope (IC-coherent) relaxed accessors — proven r3..r12 primitives
__device__ __forceinline__ void st_ic_u32(unsigned int* p, unsigned int v) {
    __hip_atomic_store(p, v, __ATOMIC_RELAXED, __HIP_MEMORY_SCOPE_AGENT);
}
__device__ __forceinline__ unsigned int ld_ic_u32(const unsigned int* p) {
    return __hip_atomic_load(p, __ATOMIC_RELAXED, __HIP_MEMORY_SCOPE_AGENT);
}

// ---------------------------------------------------------------------------
// Generic f32 tiled GEMM: C[M,N] = A[M,K] @ B[N,K]^T (+bias1+bias2 on z==0).
// ---------------------------------------------------------------------------
__global__ void gemm_nt_bias(const float* __restrict__ A, int lda,
                             const float* __restrict__ B, int ldb,
                             float* __restrict__ C, int ldc, int K,
                             const float* __restrict__ bias1,
                             const float* __restrict__ bias2)
{
    __shared__ float As[32 * 68];
    __shared__ float Bs[32 * 68];
    const int tid = threadIdx.x;
    const int m0 = blockIdx.y * 64, n0 = blockIdx.x * 64;
    const int kchunk = K / gridDim.z;
    const int kbeg = blockIdx.z * kchunk, kend = kbeg + kchunk;
    const int tr = tid >> 4, tc = tid & 15;
    float acc[4][4] = {};

    for (int k0 = kbeg; k0 < kend; k0 += 32) {
        __syncthreads();
        #pragma unroll
        for (int idx = tid; idx < 2048; idx += TPB) {
            const int r = idx >> 5, kk = idx & 31;
            As[kk * 68 + r] = A[(size_t)(m0 + r) * lda + k0 + kk];
            Bs[kk * 68 + r] = B[(size_t)(n0 + r) * ldb + k0 + kk];
        }
        __syncthreads();
        #pragma unroll
        for (int kk = 0; kk < 32; ++kk) {
            const f32x4 a = *(const f32x4*)&As[kk * 68 + tr * 4];
            const f32x4 b = *(const f32x4*)&Bs[kk * 68 + tc * 4];
            #pragma unroll
            for (int i = 0; i < 4; ++i)
                #pragma unroll
                for (int j = 0; j < 4; ++j)
                    acc[i][j] = fmaf(a[i], b[j], acc[i][j]);
        }
    }

    const bool split = (gridDim.z > 1);
    #pragma unroll
    for (int i = 0; i < 4; ++i) {
        const int m = m0 + tr * 4 + i;
        #pragma unroll
        for (int j = 0; j < 4; ++j) {
            const int n = n0 + tc * 4 + j;
            float v = acc[i][j];
            if (blockIdx.z == 0) {
                if (bias1) v += bias1[n];
                if (bias2) v += bias2[n];
            }
            if (split) atomicAdd(&C[(size_t)m * ldc + n], v);
            else       C[(size_t)m * ldc + n] = v;
        }
    }
}

// ---------------------------------------------------------------------------
// LSTM recurrence. 64 WGs x 256 threads. 2-D partition, split-K per wave.
// flags: 256 per-WAVE slots (wg*4+wv), 64B apart. flag = t+2 after step t.
// ---------------------------------------------------------------------------
__global__ void __launch_bounds__(TPB, 1)
lstm_seq(const float* __restrict__ Whh,   // [2048,512] f32
         const float* __restrict__ GX0,   // [64,2048] f32 (ws)
         const float* __restrict__ P,     // [512,2048] f32 (ws)
         const int*   __restrict__ x2,    // [64,512]
         const int*   __restrict__ lens,  // [64]
         _Float16*    hbuf,               // [2][64*512] f16 (ws, IC-resident)
         float*       __restrict__ hn,    // [64,512] f32 (ws)
         unsigned int* flags)             // [256 wave-slots] spaced 64B
{
    // Spart[buf][wv][rowloc(128)][16 batch slots + pad4] — DOUBLE buffered
    __shared__ float Spart[2 * 4 * 128 * 20];   // 81920 B

    const int tid = threadIdx.x, wg = blockIdx.x;
    const int lane = tid & 63, wv = tid >> 6;
    const int BG = wg >> 4;               // batch group 0..3
    const int CG = wg & 15;               // col group 0..15
    const int m16 = lane & 15, q = lane >> 4;

    // ---- gate-thread geometry: thread -> (batch-loc, 2 adjacent cols) ----
    const int bl  = tid >> 4;             // 0..15 batch-local
    const int cq  = (tid & 15) * 2;       // 0,2,..,30 col-local
    const int b   = BG * 16 + bl;
    const int col = CG * 32 + cq;
    const int last = lens[b] - 1;
    const int* toks = x2 + b * 512;

    // ---- publish h_0 = 0 (my cells); per-wave flag := 1 ASAP ----
    { f16x2 z; z[0] = (_Float16)0.f; z[1] = (_Float16)0.f;
      st_ic_u32((unsigned int*)(hbuf + b * 512 + col),
                __builtin_bit_cast(unsigned int, z)); }
    asm volatile("s_waitcnt vmcnt(0)" ::: "memory");
    unsigned int* myflag = flags + (size_t)(wg * 4 + wv) * 16;  // 64B spacing
    if (lane == 0) st_ic_u32(myflag, 1u);

    // ---- time-invariant gate inputs from GX0 (hoisted) ----
    f32x2 gxv[4];
    {
        const float* gx = GX0 + (size_t)b * 2048 + col;
        #pragma unroll
        for (int g = 0; g < 4; ++g) gxv[g] = *(const f32x2*)(gx + g * 512);
    }

    // wave wv consumes h-cols [128wv,128wv+128) of batch group BG, produced
    // by WGs (BG, 4wv+0..3) x waves 0..3: poll those 16 per-wave flags.
    const unsigned int* pollp =
        flags + (size_t)(BG * 64 + wv * 16 + (lane & 15)) * 16;

    // ---- B fragments: wave wv's 8 n-tiles x 4 K-frags (128 VGPRs) ----
    f16x8 bfr[8][4];
    #pragma unroll
    for (int n = 0; n < 8; ++n) {
        const int rr = n * 16 + m16;
        const int gr = (rr >> 5) * 512 + CG * 32 + (rr & 31);
        const float* wrow = Whh + (size_t)gr * 512 + wv * 128 + q * 8;
        #pragma unroll
        for (int ks = 0; ks < 4; ++ks) {
            const f32x4 w0 = *(const f32x4*)(wrow + ks * 32);
            const f32x4 w1 = *(const f32x4*)(wrow + ks * 32 + 4);
            f16x8 bv;
            #pragma unroll
            for (int e = 0; e < 4; ++e) {
                bv[e]     = (_Float16)w0[e];
                bv[4 + e] = (_Float16)w1[e];
            }
            bfr[n][ks] = bv;
        }
    }

    // ---- P-row pipeline: ppv = row for step t; refilled post-release ----
    int tok1;
    f32x2 ppv[4];
    {
        const int tok0 = toks[0];
        const float* pp = P + (size_t)tok0 * 2048 + col;
        #pragma unroll
        for (int g = 0; g < 4; ++g) ppv[g] = *(const f32x2*)(pp + g * 512);
        tok1 = toks[1];
    }

    float c0 = 0.f, c1 = 0.f;

    for (int t = 0; t < 512; ++t) {
        const unsigned int tgt = (unsigned int)(t + 1);

        // ---- per-wave arrival detection: poll my 16 producer-wave flags ----
        while (true) {
            const unsigned int v = ld_ic_u32(pollp);
            if (__all((int)(v >= tgt))) break;
        }
        asm volatile("" ::: "memory");

        const _Float16* hsrc = hbuf + (size_t)(t & 1) * (64 * 512);
        _Float16*       hdst = hbuf + (size_t)((t + 1) & 1) * (64 * 512);

        // ---- A fragments: 4 x dwordx4 sc1 (4KB/wave from IC); the
        //      vmcnt(0) also drains last step's P prefetch (poll shadow) ----
        u32x4 a0, a1, a2, a3;
        {
            const _Float16* ap =
                hsrc + (BG * 16 + m16) * 512 + wv * 128 + q * 8;
            asm volatile(
                "global_load_dwordx4 %0, %4, off sc1\n\t"
                "global_load_dwordx4 %1, %4, off offset:64 sc1\n\t"
                "global_load_dwordx4 %2, %4, off offset:128 sc1\n\t"
                "global_load_dwordx4 %3, %4, off offset:192 sc1\n\t"
                "s_waitcnt vmcnt(0)"
                : "=&v"(a0), "=&v"(a1), "=&v"(a2), "=&v"(a3)
                : "v"(ap)
                : "memory");
        }
        f16x8 af[4] = {
            __builtin_bit_cast(f16x8, a0), __builtin_bit_cast(f16x8, a1),
            __builtin_bit_cast(f16x8, a2), __builtin_bit_cast(f16x8, a3)
        };

        // ---- 32 MFMA: 8 n-tiles x 4 K-steps (my K-chunk partial) ----
        f32x4 acc[8] = {};
        #pragma unroll
        for (int ks = 0; ks < 4; ++ks)
            #pragma unroll
            for (int n = 0; n < 8; ++n)
                acc[n] = __builtin_amdgcn_mfma_f32_16x16x32_f16(
                    af[ks], bfr[n][ks], acc[n], 0, 0, 0);

        // ---- write partial S to LDS buf t&1, batch-granule rotated by
        //      (row>>3)&3 so both write and reduce-read are 2-way (free) ----
        float* sp = Spart + (t & 1) * 10240;
        {
            const int cl = lane & 15, gq = lane >> 4;
            #pragma unroll
            for (int n = 0; n < 8; ++n) {
                const int row = wv * 128 + n * 16 + cl;
                *(f32x4*)&sp[row * 20 + ((gq + (row >> 3)) & 3) * 4] = acc[n];
            }
        }
        __syncthreads();                  // split-K reduction barrier (only one)

        // ---- gate inputs: sum 4 wave-partials per gate value ----
        f32x2 sv[4];
        #pragma unroll
        for (int g = 0; g < 4; ++g) {
            f32x2 s = {0.f, 0.f};
            #pragma unroll
            for (int w = 0; w < 4; ++w) {
                const int r0 = w * 128 + g * 32 + cq;
                const int base =
                    r0 * 20 + (((bl >> 2) + (r0 >> 3)) & 3) * 4 + (bl & 3);
                s[0] += sp[base];
                s[1] += sp[base + 20];    // col cq+1: same rotation (cq even)
            }
            sv[g] = s;
        }

        // ---- gates (2 adjacent cols of one batch per thread) ----
        float hv[2];
        #pragma unroll
        for (int p = 0; p < 2; ++p) {
            const float iv = sigm_(sv[0][p] + gxv[0][p] + ppv[0][p]);
            const float fv = sigm_(sv[1][p] + gxv[1][p] + ppv[1][p]);
            const float gv = tanh_(sv[2][p] + gxv[2][p] + ppv[2][p]);
            const float ov = sigm_(sv[3][p] + gxv[3][p] + ppv[3][p]);
            float& c = p ? c1 : c0;
            c = fv * c + iv * gv;
            hv[p] = ov * tanh_(c);
        }

        f16x2 hh; hh[0] = (_Float16)hv[0]; hh[1] = (_Float16)hv[1];
        st_ic_u32((unsigned int*)(hdst + b * 512 + col),
                  __builtin_bit_cast(unsigned int, hh));
        if (t == last) {
            f32x2 o; o[0] = hv[0]; o[1] = hv[1];
            *(f32x2*)(hn + (size_t)b * 512 + col) = o;
        }

        // ---- per-wave release: drain MY stores, then lane0 flag. No bar2,
        //      no WG-straggler wait. ----
        asm volatile("s_waitcnt vmcnt(0)" ::: "memory");
        if (lane == 0) st_ic_u32(myflag, (unsigned int)(t + 2));

        // ---- NEXT step's P row prefetch issued POST-release; its latency
        //      parks in the poll window (drained by A-load's vmcnt(0)) ----
        {
            const float* pn = P + (size_t)tok1 * 2048 + col;
            #pragma unroll
            for (int g = 0; g < 4; ++g)
                ppv[g] = *(const f32x2*)(pn + g * 512);
            tok1 = toks[t < 510 ? t + 2 : 511];
        }
    }
}

// ---------------------------------------------------------------------------
extern "C" void kernel_launch(void* const* d_in, const int* in_sizes, int n_in,
                              void* d_out, int out_size, void* d_ws, size_t ws_size,
                              hipStream_t stream)
{
    const float* x1    = (const float*)d_in[0];   // [64,1024]
    const int*   x2    = (const int*)  d_in[1];   // [64,512]
    const int*   lens  = (const int*)  d_in[2];   // [64]
    const float* emb   = (const float*)d_in[3];   // [512,128]
    const float* W_ih  = (const float*)d_in[4];   // [2048,1152]
    const float* W_hh  = (const float*)d_in[5];   // [2048,512]
    const float* b_ih  = (const float*)d_in[6];   // [2048]
    const float* b_hh  = (const float*)d_in[7];   // [2048]
    const float* W_act = (const float*)d_in[8];   // [512,512]
    const float* b_act = (const float*)d_in[9];   // [512]
    float* out = (float*)d_out;                   // [64,512]

    char* ws = (char*)d_ws;
    float*        GX0   = (float*)(ws + WS_GX0);
    float*        P     = (float*)(ws + WS_P);
    float*        hn    = (float*)(ws + WS_HN);
    _Float16*     hbuf  = (_Float16*)(ws + WS_HBUF);
    unsigned int* flags = (unsigned int*)(ws + WS_FLAGS);

    // zero flags + k-split accumulators (ws/out poisoned 0xAA each call)
    hipMemsetAsync(flags, 0, 16384, stream);
    hipMemsetAsync(GX0, 0, 64 * 2048 * sizeof(float), stream);
    hipMemsetAsync(out, 0, 64 * 512 * sizeof(float), stream);

    // GX0 = x1 @ W_ih[:, :1024]^T + b_ih + b_hh    (K=1024, 4-way K-split)
    gemm_nt_bias<<<dim3(32, 1, 4), TPB, 0, stream>>>(
        x1, 1024, W_ih, 1152, GX0, 2048, 1024, b_ih, b_hh);
    // P = emb @ W_ih[:, 1024:]^T                   (K=128)
    gemm_nt_bias<<<dim3(32, 8, 1), TPB, 0, stream>>>(
        emb, 128, W_ih + 1024, 1152, P, 2048, 128, nullptr, nullptr);

    // recurrence: 64 WGs, per-wave flags, double-buffered split-K LDS
    lstm_seq<<<NWG, TPB, 0, stream>>>(W_hh, GX0, P, x2, lens, hbuf, hn, flags);

    // out = hn @ W_act^T + b_act                   (K=512, 4-way K-split)
    gemm_nt_bias<<<dim3(8, 1, 4), TPB, 0, stream>>>(
        hn, 512, W_act, 512, out, 512, 512, b_act, nullptr);
}

// Round 3
// 1375.084 us; speedup vs baseline: 1.3150x; 1.2427x over previous
//
#include <hip/hip_runtime.h>
#include <cstdint>
#include <cstddef>

// ===========================================================================
// ActionDecoder on MI355X — round 15: EXACT r12 sync core (proven best,
// lstm 1285us / total 1454us) + ONE isolated change: Spart batch-granule
// rotation (validated on the conflict counter in r14: 2.5e7 -> 8.4e6).
//
// r14 post-mortem (REVERTED here): per-wave flags + no-bar2 cost ~+300us.
// bar2 aggregates the 4 waves' store-drains locally (CU-speed) and publishes
// ONE IC flag line per WG; consumers watch 4 lines. Per-wave flags paid 16
// independent IC publications and detect = max over 16 tails -> slower.
//
// r15 change: split-K partials in Spart are written/read with the batch
// granule rotated by (row>>3)&3:
//   write: slot p = (gq + (row>>3)) & 3     (b128-preserving)
//   read:  p = ((bl>>2) + (row>>3)) & 3, elem bl&3
// Both sides become 2-way bank aliasing (free, m136) instead of 4-way.
// The +20 col-pair read keeps the same rotation (cq even, never crosses an
// 8-row boundary).
//
// Topology (r7/r12): 64 WGs, WG w = (BG = w>>4, CG = w&15) owns batch-group
// BG (16 batches) x col-group CG (32 h-cols = 128 gate rows of W_hh). Wave
// wv takes K-chunk [128wv,128wv+128): B-frags in 128 VGPRs; split-K partial
// S in single-buffered LDS (pitch 20, b128 writes), two __syncthreads/step
// (reduce barrier + release barrier), tid0 stores the single WG flag;
// consumers poll 4 producer flags per wave. Cross-WG data/flags: relaxed
// agent-scope intrinsics (sc1 -> IC-coherent, no fences). P-row prefetch
// issued POST-release so its latency parks in the poll window.
// ===========================================================================

typedef _Float16     f16x8 __attribute__((ext_vector_type(8)));
typedef _Float16     f16x2 __attribute__((ext_vector_type(2)));
typedef float        f32x4 __attribute__((ext_vector_type(4)));
typedef float        f32x2 __attribute__((ext_vector_type(2)));
typedef unsigned int u32x4 __attribute__((ext_vector_type(4)));

#define TPB 256
#define NWG 64

// ---- ws layout (bytes) ----
#define WS_GX0   0          // 64*2048 f32   = 524288
#define WS_P     524288     // 512*2048 f32  = 4194304
#define WS_HN    4718592    // 64*512 f32    = 131072
#define WS_HBUF  4849664    // 2*64*512 f16  = 131072
#define WS_FLAGS 4980736    // 64 WG x 256B  = 16384

__device__ __forceinline__ float sigm_(float x) { return 1.f / (1.f + __expf(-x)); }
__device__ __forceinline__ float tanh_(float x) {
    const float e = __expf(-2.f * fabsf(x));
    return copysignf((1.f - e) / (1.f + e), x);
}

// agent-scope (IC-coherent) relaxed accessors — proven r3..r12 primitives
__device__ __forceinline__ void st_ic_u32(unsigned int* p, unsigned int v) {
    __hip_atomic_store(p, v, __ATOMIC_RELAXED, __HIP_MEMORY_SCOPE_AGENT);
}
__device__ __forceinline__ unsigned int ld_ic_u32(const unsigned int* p) {
    return __hip_atomic_load(p, __ATOMIC_RELAXED, __HIP_MEMORY_SCOPE_AGENT);
}

// ---------------------------------------------------------------------------
// Generic f32 tiled GEMM: C[M,N] = A[M,K] @ B[N,K]^T (+bias1+bias2 on z==0).
// ---------------------------------------------------------------------------
__global__ void gemm_nt_bias(const float* __restrict__ A, int lda,
                             const float* __restrict__ B, int ldb,
                             float* __restrict__ C, int ldc, int K,
                             const float* __restrict__ bias1,
                             const float* __restrict__ bias2)
{
    __shared__ float As[32 * 68];
    __shared__ float Bs[32 * 68];
    const int tid = threadIdx.x;
    const int m0 = blockIdx.y * 64, n0 = blockIdx.x * 64;
    const int kchunk = K / gridDim.z;
    const int kbeg = blockIdx.z * kchunk, kend = kbeg + kchunk;
    const int tr = tid >> 4, tc = tid & 15;
    float acc[4][4] = {};

    for (int k0 = kbeg; k0 < kend; k0 += 32) {
        __syncthreads();
        #pragma unroll
        for (int idx = tid; idx < 2048; idx += TPB) {
            const int r = idx >> 5, kk = idx & 31;
            As[kk * 68 + r] = A[(size_t)(m0 + r) * lda + k0 + kk];
            Bs[kk * 68 + r] = B[(size_t)(n0 + r) * ldb + k0 + kk];
        }
        __syncthreads();
        #pragma unroll
        for (int kk = 0; kk < 32; ++kk) {
            const f32x4 a = *(const f32x4*)&As[kk * 68 + tr * 4];
            const f32x4 b = *(const f32x4*)&Bs[kk * 68 + tc * 4];
            #pragma unroll
            for (int i = 0; i < 4; ++i)
                #pragma unroll
                for (int j = 0; j < 4; ++j)
                    acc[i][j] = fmaf(a[i], b[j], acc[i][j]);
        }
    }

    const bool split = (gridDim.z > 1);
    #pragma unroll
    for (int i = 0; i < 4; ++i) {
        const int m = m0 + tr * 4 + i;
        #pragma unroll
        for (int j = 0; j < 4; ++j) {
            const int n = n0 + tc * 4 + j;
            float v = acc[i][j];
            if (blockIdx.z == 0) {
                if (bias1) v += bias1[n];
                if (bias2) v += bias2[n];
            }
            if (split) atomicAdd(&C[(size_t)m * ldc + n], v);
            else       C[(size_t)m * ldc + n] = v;
        }
    }
}

// ---------------------------------------------------------------------------
// LSTM recurrence. 64 WGs x 256 threads. 2-D partition, split-K per wave.
// ---------------------------------------------------------------------------
__global__ void __launch_bounds__(TPB, 1)
lstm_seq(const float* __restrict__ Whh,   // [2048,512] f32
         const float* __restrict__ GX0,   // [64,2048] f32 (ws)
         const float* __restrict__ P,     // [512,2048] f32 (ws)
         const int*   __restrict__ x2,    // [64,512]
         const int*   __restrict__ lens,  // [64]
         _Float16*    hbuf,               // [2][64*512] f16 (ws, IC-resident)
         float*       __restrict__ hn,    // [64,512] f32 (ws)
         unsigned int* flags)             // [64 wg] spaced 256B
{
    // Spart[wv][rowloc(128)][16 batch slots + pad4] f32 = 40960 B
    __shared__ float Spart[4 * 128 * 20];

    const int tid = threadIdx.x, wg = blockIdx.x;
    const int lane = tid & 63, wv = tid >> 6;
    const int BG = wg >> 4;               // batch group 0..3
    const int CG = wg & 15;               // col group 0..15
    const int m16 = lane & 15, q = lane >> 4;

    // ---- gate-thread geometry: thread -> (batch-loc, 2 adjacent cols) ----
    const int bl  = tid >> 4;             // 0..15 batch-local
    const int cq  = (tid & 15) * 2;       // 0,2,..,30 col-local
    const int b   = BG * 16 + bl;
    const int col = CG * 32 + cq;
    const int last = lens[b] - 1;
    const int* toks = x2 + b * 512;

    // ---- time-invariant gate inputs from GX0 (hoisted) ----
    f32x2 gxv[4];
    {
        const float* gx = GX0 + (size_t)b * 2048 + col;
        #pragma unroll
        for (int g = 0; g < 4; ++g) gxv[g] = *(const f32x2*)(gx + g * 512);
    }

    // ---- publish h_0 = 0 (my cells); WG flag := 1 ----
    { f16x2 z; z[0] = (_Float16)0.f; z[1] = (_Float16)0.f;
      st_ic_u32((unsigned int*)(hbuf + b * 512 + col),
                __builtin_bit_cast(unsigned int, z)); }
    __syncthreads();                      // drains vmcnt of all waves
    unsigned int* myflag = flags + (size_t)wg * 64;   // 256B spacing
    if (tid == 0) st_ic_u32(myflag, 1u);

    // wave wv consumes h-cols [128wv,128wv+128) of batch group BG,
    // produced by WGs (BG, 4wv+0..3): poll those 4 flags (lane&3).
    const unsigned int* pollp =
        flags + (size_t)(BG * 16 + wv * 4 + (lane & 3)) * 64;

    // ---- B fragments: wave wv's 8 n-tiles x 4 K-frags (128 VGPRs) ----
    f16x8 bfr[8][4];
    #pragma unroll
    for (int n = 0; n < 8; ++n) {
        const int rr = n * 16 + m16;
        const int gr = (rr >> 5) * 512 + CG * 32 + (rr & 31);
        const float* wrow = Whh + (size_t)gr * 512 + wv * 128 + q * 8;
        #pragma unroll
        for (int ks = 0; ks < 4; ++ks) {
            const f32x4 w0 = *(const f32x4*)(wrow + ks * 32);
            const f32x4 w1 = *(const f32x4*)(wrow + ks * 32 + 4);
            f16x8 bv;
            #pragma unroll
            for (int e = 0; e < 4; ++e) {
                bv[e]     = (_Float16)w0[e];
                bv[4 + e] = (_Float16)w1[e];
            }
            bfr[n][ks] = bv;
        }
    }

    // ---- P-row pipeline: ppv = row for step t; refilled post-release ----
    int tok1;
    f32x2 ppv[4];
    {
        const int tok0 = toks[0];
        const float* pp = P + (size_t)tok0 * 2048 + col;
        #pragma unroll
        for (int g = 0; g < 4; ++g) ppv[g] = *(const f32x2*)(pp + g * 512);
        tok1 = toks[1];
    }

    float c0 = 0.f, c1 = 0.f;

    for (int t = 0; t < 512; ++t) {
        const unsigned int tgt = (unsigned int)(t + 1);

        // ---- per-wave arrival detection: poll my 4 producer flags ----
        while (true) {
            const unsigned int v = ld_ic_u32(pollp);
            if (__all((int)(v >= tgt))) break;
        }
        asm volatile("" ::: "memory");

        const _Float16* hsrc = hbuf + (size_t)(t & 1) * (64 * 512);
        _Float16*       hdst = hbuf + (size_t)((t + 1) & 1) * (64 * 512);

        // ---- A fragments: 4 x dwordx4 sc1 (4KB/wave from IC) ----
        u32x4 a0, a1, a2, a3;
        {
            const _Float16* ap =
                hsrc + (BG * 16 + m16) * 512 + wv * 128 + q * 8;
            asm volatile(
                "global_load_dwordx4 %0, %4, off sc1\n\t"
                "global_load_dwordx4 %1, %4, off offset:64 sc1\n\t"
                "global_load_dwordx4 %2, %4, off offset:128 sc1\n\t"
                "global_load_dwordx4 %3, %4, off offset:192 sc1\n\t"
                "s_waitcnt vmcnt(0)"
                : "=&v"(a0), "=&v"(a1), "=&v"(a2), "=&v"(a3)
                : "v"(ap)
                : "memory");
        }
        f16x8 af[4] = {
            __builtin_bit_cast(f16x8, a0), __builtin_bit_cast(f16x8, a1),
            __builtin_bit_cast(f16x8, a2), __builtin_bit_cast(f16x8, a3)
        };

        // ---- 32 MFMA: 8 n-tiles x 4 K-steps (my K-chunk partial) ----
        f32x4 acc[8] = {};
        #pragma unroll
        for (int ks = 0; ks < 4; ++ks)
            #pragma unroll
            for (int n = 0; n < 8; ++n)
                acc[n] = __builtin_amdgcn_mfma_f32_16x16x32_f16(
                    af[ks], bfr[n][ks], acc[n], 0, 0, 0);

        // ---- write partial S to LDS, batch granule rotated by (row>>3)&3:
        //      write slot p = (gq + row>>3)&3 — b128-preserving, 2-way ----
        {
            const int cl = lane & 15, gq = lane >> 4;
            #pragma unroll
            for (int n = 0; n < 8; ++n) {
                const int row = wv * 128 + n * 16 + cl;
                *(f32x4*)&Spart[row * 20 + ((gq + (row >> 3)) & 3) * 4] = acc[n];
            }
        }
        __syncthreads();                  // split-K reduction barrier

        // ---- gate inputs: sum 4 wave-partials per gate value (2-way) ----
        f32x2 sv[4];
        #pragma unroll
        for (int g = 0; g < 4; ++g) {
            f32x2 s = {0.f, 0.f};
            #pragma unroll
            for (int w = 0; w < 4; ++w) {
                const int r0 = w * 128 + g * 32 + cq;
                const int base =
                    r0 * 20 + (((bl >> 2) + (r0 >> 3)) & 3) * 4 + (bl & 3);
                s[0] += Spart[base];
                s[1] += Spart[base + 20]; // col cq+1: same rotation (cq even)
            }
            sv[g] = s;
        }

        // ---- gates (2 adjacent cols of one batch per thread) ----
        float hv[2];
        #pragma unroll
        for (int p = 0; p < 2; ++p) {
            const float iv = sigm_(sv[0][p] + gxv[0][p] + ppv[0][p]);
            const float fv = sigm_(sv[1][p] + gxv[1][p] + ppv[1][p]);
            const float gv = tanh_(sv[2][p] + gxv[2][p] + ppv[2][p]);
            const float ov = sigm_(sv[3][p] + gxv[3][p] + ppv[3][p]);
            float& c = p ? c1 : c0;
            c = fv * c + iv * gv;
            hv[p] = ov * tanh_(c);
        }

        f16x2 hh; hh[0] = (_Float16)hv[0]; hh[1] = (_Float16)hv[1];
        st_ic_u32((unsigned int*)(hdst + b * 512 + col),
                  __builtin_bit_cast(unsigned int, hh));
        if (t == last) {
            f32x2 o; o[0] = hv[0]; o[1] = hv[1];
            *(f32x2*)(hn + (size_t)b * 512 + col) = o;
        }

        // ---- release: barrier drains h stores ONLY (no P loads in
        //      flight now), then tid0 flag ----
        __syncthreads();
        if (tid == 0) st_ic_u32(myflag, (unsigned int)(t + 2));

        // ---- NEXT step's P row prefetch issued POST-release; its
        //      (possibly HBM-miss) latency sits in the poll window ----
        {
            const float* pn = P + (size_t)tok1 * 2048 + col;
            #pragma unroll
            for (int g = 0; g < 4; ++g)
                ppv[g] = *(const f32x2*)(pn + g * 512);
            tok1 = toks[t < 510 ? t + 2 : 511];
        }
    }
}

// ---------------------------------------------------------------------------
extern "C" void kernel_launch(void* const* d_in, const int* in_sizes, int n_in,
                              void* d_out, int out_size, void* d_ws, size_t ws_size,
                              hipStream_t stream)
{
    const float* x1    = (const float*)d_in[0];   // [64,1024]
    const int*   x2    = (const int*)  d_in[1];   // [64,512]
    const int*   lens  = (const int*)  d_in[2];   // [64]
    const float* emb   = (const float*)d_in[3];   // [512,128]
    const float* W_ih  = (const float*)d_in[4];   // [2048,1152]
    const float* W_hh  = (const float*)d_in[5];   // [2048,512]
    const float* b_ih  = (const float*)d_in[6];   // [2048]
    const float* b_hh  = (const float*)d_in[7];   // [2048]
    const float* W_act = (const float*)d_in[8];   // [512,512]
    const float* b_act = (const float*)d_in[9];   // [512]
    float* out = (float*)d_out;                   // [64,512]

    char* ws = (char*)d_ws;
    float*        GX0   = (float*)(ws + WS_GX0);
    float*        P     = (float*)(ws + WS_P);
    float*        hn    = (float*)(ws + WS_HN);
    _Float16*     hbuf  = (_Float16*)(ws + WS_HBUF);
    unsigned int* flags = (unsigned int*)(ws + WS_FLAGS);

    // zero flags + k-split accumulators (ws/out poisoned 0xAA each call)
    hipMemsetAsync(flags, 0, 16384, stream);
    hipMemsetAsync(GX0, 0, 64 * 2048 * sizeof(float), stream);
    hipMemsetAsync(out, 0, 64 * 512 * sizeof(float), stream);

    // GX0 = x1 @ W_ih[:, :1024]^T + b_ih + b_hh    (K=1024, 4-way K-split)
    gemm_nt_bias<<<dim3(32, 1, 4), TPB, 0, stream>>>(
        x1, 1024, W_ih, 1152, GX0, 2048, 1024, b_ih, b_hh);
    // P = emb @ W_ih[:, 1024:]^T                   (K=128)
    gemm_nt_bias<<<dim3(32, 8, 1), TPB, 0, stream>>>(
        emb, 128, W_ih + 1024, 1152, P, 2048, 128, nullptr, nullptr);

    // recurrence: 64 WGs, 2-D partition, per-wave 4-flag polling
    lstm_seq<<<NWG, TPB, 0, stream>>>(W_hh, GX0, P, x2, lens, hbuf, hn, flags);

    // out = hn @ W_act^T + b_act                   (K=512, 4-way K-split)
    gemm_nt_bias<<<dim3(8, 1, 4), TPB, 0, stream>>>(
        hn, 512, W_act, 512, out, 512, 512, b_act, nullptr);
}